// Round 3
// baseline (899.849 us; speedup 1.0000x reference)
//
#include <hip/hip_runtime.h>
#include <math.h>

#define NN 16384
#define BB 128
#define FF 32
#define RR 20
#define EE 262144

__device__ __forceinline__ float sspf(float x) {
  // softplus(x) - log(2), numerically stable
  return fmaxf(x, 0.0f) + log1pf(expf(-fabsf(x))) - 0.69314718055994531f;
}

// Pin a float into a VGPR: value becomes opaque -> compiler cannot
// rematerialize the load inside a later loop; must keep it resident.
#define PIN(v) asm volatile("" : "+v"(v))

// ---------------- K1: node embeddings hsv[n*32+f] = {hs, hvx, hvy, hvz} ----------------
__global__ __launch_bounds__(256) void k_embed(const float* __restrict__ x,
        const float* __restrict__ ws, const float* __restrict__ wv,
        float4* __restrict__ hsv) {
  int tid = blockIdx.x * 256 + threadIdx.x;   // N*8 threads
  int n = tid >> 3, fq = tid & 7;
  const float* xr = x + (size_t)n * 512;
  float acc[4][4];
#pragma unroll
  for (int k = 0; k < 4; k++)
#pragma unroll
    for (int c = 0; c < 4; c++) acc[k][c] = 0.f;
  for (int bq = 0; bq < 32; bq++) {
    float4 xs4 = *(const float4*)(xr + 4 * bq);
    float4 a0 = *(const float4*)(xr + 128 + 12 * bq);
    float4 a1 = *(const float4*)(xr + 128 + 12 * bq + 4);
    float4 a2 = *(const float4*)(xr + 128 + 12 * bq + 8);
    float xsv[4] = {xs4.x, xs4.y, xs4.z, xs4.w};
    float vv[4][3];
    vv[0][0] = a0.x; vv[0][1] = a0.y; vv[0][2] = a0.z;
    vv[1][0] = a0.w; vv[1][1] = a1.x; vv[1][2] = a1.y;
    vv[2][0] = a1.z; vv[2][1] = a1.w; vv[2][2] = a2.x;
    vv[3][0] = a2.y; vv[3][1] = a2.z; vv[3][2] = a2.w;
#pragma unroll
    for (int bb = 0; bb < 4; bb++) {
      int b = 4 * bq + bb;
      float4 w_s = *(const float4*)(ws + b * 32 + 4 * fq);
      float4 w_v = *(const float4*)(wv + b * 32 + 4 * fq);
      float wsx[4] = {w_s.x, w_s.y, w_s.z, w_s.w};
      float wvx[4] = {w_v.x, w_v.y, w_v.z, w_v.w};
#pragma unroll
      for (int k = 0; k < 4; k++) {
        acc[k][0] += xsv[bb] * wsx[k];
        acc[k][1] += vv[bb][0] * wvx[k];
        acc[k][2] += vv[bb][1] * wvx[k];
        acc[k][3] += vv[bb][2] * wvx[k];
      }
    }
  }
  const float sc = 0.088388347648318447f;  // 1/sqrt(128)
#pragma unroll
  for (int k = 0; k < 4; k++) {
    float4 o;
    o.x = acc[k][0] * sc; o.y = acc[k][1] * sc;
    o.z = acc[k][2] * sc; o.w = acc[k][3] * sc;
    hsv[(size_t)n * 32 + 4 * fq + k] = o;
  }
}

// ---------------- CSR build ----------------
__global__ __launch_bounds__(256) void k_count(const int* __restrict__ idx_i,
        int* __restrict__ cnt, int* __restrict__ pos) {
  int e = blockIdx.x * 256 + threadIdx.x;
  pos[e] = atomicAdd(cnt + idx_i[e], 1);
}

__global__ __launch_bounds__(256) void k_scan(const int* __restrict__ cnt,
        int* __restrict__ offs) {
  __shared__ int part[256];
  int t = threadIdx.x;
  int s = 0;
  for (int i = t * 64; i < t * 64 + 64; ++i) s += cnt[i];
  part[t] = s;
  __syncthreads();
  if (t == 0) {
    int run = 0;
    for (int i = 0; i < 256; i++) { int v = part[i]; part[i] = run; run += v; }
    offs[NN] = run;
  }
  __syncthreads();
  int run = part[t];
  for (int i = t * 64; i < t * 64 + 64; ++i) { offs[i] = run; run += cnt[i]; }
}

__global__ __launch_bounds__(256) void k_fill(const int* __restrict__ idx_i,
        const int* __restrict__ pos, const int* __restrict__ offs,
        int* __restrict__ elist) {
  int e = blockIdx.x * 256 + threadIdx.x;
  elist[offs[idx_i[e]] + pos[e]] = e;
}

// ---------------- KA: per-edge filter MLP first layer: h = ssp(f_ij @ W1 + b1) ----------------
__global__ __launch_bounds__(256) void k_h(const float* __restrict__ fij,
        const float* __restrict__ W1, const float* __restrict__ b1,
        float* __restrict__ hout) {
  __shared__ float sfij[20 * 256];   // [r][edge_local]
  __shared__ float sW1[640];
  __shared__ float sb1[32];
  int t = threadIdx.x;
  int e0 = blockIdx.x * 256;
  for (int i = t; i < 5120; i += 256) {
    float v = fij[(size_t)e0 * 20 + i];
    int el = i / 20, r = i - el * 20;
    sfij[r * 256 + el] = v;
  }
  for (int i = t; i < 640; i += 256) sW1[i] = W1[i];
  if (t < 32) sb1[t] = b1[t];
  __syncthreads();
  int fq = t & 3, el = t >> 2;   // el 0..63 (4 edges each), fq 0..3 (8 fp each)
  int fp0 = fq * 8;
  float acc[4][8];
#pragma unroll
  for (int j = 0; j < 4; j++)
#pragma unroll
    for (int i = 0; i < 8; i++) acc[j][i] = sb1[fp0 + i];
#pragma unroll
  for (int r = 0; r < 20; r++) {
    float4 fe4 = *(const float4*)(sfij + r * 256 + el * 4);
    float fe[4] = {fe4.x, fe4.y, fe4.z, fe4.w};
    float4 wA = *(const float4*)(sW1 + r * 32 + fp0);
    float4 wB = *(const float4*)(sW1 + r * 32 + fp0 + 4);
    float w[8] = {wA.x, wA.y, wA.z, wA.w, wB.x, wB.y, wB.z, wB.w};
#pragma unroll
    for (int j = 0; j < 4; j++)
#pragma unroll
      for (int i = 0; i < 8; i++) acc[j][i] += fe[j] * w[i];
  }
#pragma unroll
  for (int j = 0; j < 4; j++) {
    float4 o1, o2;
    o1.x = sspf(acc[j][0]); o1.y = sspf(acc[j][1]);
    o1.z = sspf(acc[j][2]); o1.w = sspf(acc[j][3]);
    o2.x = sspf(acc[j][4]); o2.y = sspf(acc[j][5]);
    o2.z = sspf(acc[j][6]); o2.w = sspf(acc[j][7]);
    size_t base = ((size_t)(e0 + el * 4 + j)) * 32 + fp0;
    *(float4*)(hout + base) = o1;
    *(float4*)(hout + base + 4) = o2;
  }
}

// ---------------- fused vector output weight: Wv = w1v @ w2v * 1/sqrt(64*128) ----------------
__global__ __launch_bounds__(256) void k_wv(const float* __restrict__ w1v,
        const float* __restrict__ w2v, float* __restrict__ Wv) {
  int o = blockIdx.x * 256 + threadIdx.x;   // 8192
  int m = o >> 7, d = o & 127;
  float s = 0.f;
  for (int b = 0; b < 128; b++) s += w1v[m * 128 + b] * w2v[b * 128 + d];
  Wv[o] = s * 0.011048543456039804f;
}

// ---------------- KB: per-edge W2 GEMV + geometric features + CSR aggregation ----------------
// ONE WAVE PER NODE. lane l: f = l>>1, owns W2 columns 6f+kb, 6f+kb+1 PINNED in
// VGPRs (asm pin defeats load rematerialization). No LDS, no barriers.
__global__ __launch_bounds__(256, 4) void k_edges(
        const float* __restrict__ h, const float* __restrict__ rcut,
        const float* __restrict__ Yr, const int* __restrict__ idxj,
        const float4* __restrict__ hsv,
        const float* __restrict__ W2, const float* __restrict__ b2,
        const int* __restrict__ offs, const int* __restrict__ elist,
        float* __restrict__ node_agg) {
  int t = threadIdx.x;
  int w = t >> 6, l = t & 63;
  int f = l >> 1, kb = (l & 1) * 2;
  int n = blockIdx.x * 4 + w;          // one node per wave, 4096 blocks
  float2 wp[32];
#pragma unroll
  for (int fp = 0; fp < 32; fp++)
    wp[fp] = *(const float2*)(W2 + fp * 192 + 6 * f + kb);   // 8B-aligned pair
#pragma unroll
  for (int fp = 0; fp < 32; fp++) { PIN(wp[fp].x); PIN(wp[fp].y); }
  float bb0 = b2[6 * f + kb], bb1 = b2[6 * f + kb + 1];
  int start = offs[n], end = offs[n + 1];
  float a0 = 0, a1 = 0, a2 = 0, a3 = 0, a4 = 0, a5 = 0;
  for (int ei = start; ei < end; ++ei) {
    int e = elist[ei];
    int j = idxj[e];
    float rc = rcut[e];
    float4 y4 = *(const float4*)(Yr + (size_t)e * 4);
    float ys = y4.x, yx = y4.y, yy = y4.z, yz = y4.w;
    float4 sv = hsv[(size_t)j * 32 + f];
    const float4* hp = (const float4*)(h + (size_t)e * 32);
    float d0 = 0.f, d1 = 0.f;
#pragma unroll
    for (int q = 0; q < 8; q++) {
      float4 h4 = hp[q];
      d0 += h4.x * wp[4 * q].x + h4.y * wp[4 * q + 1].x
          + h4.z * wp[4 * q + 2].x + h4.w * wp[4 * q + 3].x;
      d1 += h4.x * wp[4 * q].y + h4.y * wp[4 * q + 1].y
          + h4.z * wp[4 * q + 2].y + h4.w * wp[4 * q + 3].y;
    }
    float wa = (d0 + bb0) * rc, wb = (d1 + bb1) * rc;
    float s = sv.x, vx = sv.y, vy = sv.z, vz = sv.w;
    if (kb == 0) {
      a0 += s * ys * wa;                                               // ch0
      a1 += (vx * yx + vy * yy + vz * yz) * 0.57735026918962576f * wb; // ch1
    } else {
      a0 += s * yx * wa; a1 += s * yy * wa; a2 += s * yz * wa;    // ch2..4 (t_v1)
      a3 += vx * ys * wb; a4 += vy * ys * wb; a5 += vz * ys * wb; // ch5..7 (t_v2)
    }
  }
  float* na = node_agg + (size_t)n * 256;
  if (kb == 0) {
    na[f] = a0;
    na[32 + f] = a1;
  } else {
    na[64 + 3 * f + 0] = a0;  na[64 + 3 * f + 1] = a1;  na[64 + 3 * f + 2] = a2;
    na[160 + 3 * f + 0] = a3; na[160 + 3 * f + 1] = a4; na[160 + 3 * f + 2] = a5;
  }
}

// ---------------- output transforms: thread owns output column, weights PINNED in regs ----------------
__global__ __launch_bounds__(256, 4) void k_os1(const float* __restrict__ node_agg,
        const float* __restrict__ w1s, float* __restrict__ os1) {
  int t = threadIdx.x;
  int d = t & 127, sub = t >> 7;
  int sid = blockIdx.x * 2 + sub;   // 0..4095
  float wr[64];
#pragma unroll
  for (int m = 0; m < 64; m++) wr[m] = w1s[m * 128 + d];
#pragma unroll
  for (int m = 0; m < 64; m++) PIN(wr[m]);
  for (int n = sid; n < NN; n += 4096) {
    const float4* sp = (const float4*)(node_agg + (size_t)n * 256);
    float acc = 0.f;
#pragma unroll
    for (int q = 0; q < 16; q++) {
      float4 s4 = sp[q];
      acc += s4.x * wr[4 * q] + s4.y * wr[4 * q + 1]
           + s4.z * wr[4 * q + 2] + s4.w * wr[4 * q + 3];
    }
    os1[(size_t)n * 128 + d] = sspf(acc * 0.125f);   // 1/sqrt(64)
  }
}

__global__ __launch_bounds__(256, 3) void k_os2(const float* __restrict__ os1,
        const float* __restrict__ w2s, float* __restrict__ out) {
  int t = threadIdx.x;
  int d = t & 127, sub = t >> 7;
  int sid = blockIdx.x * 2 + sub;
  float wr[128];
#pragma unroll
  for (int b = 0; b < 128; b++) wr[b] = w2s[b * 128 + d];
#pragma unroll
  for (int b = 0; b < 128; b++) PIN(wr[b]);
  for (int n = sid; n < NN; n += 4096) {
    const float4* sp = (const float4*)(os1 + (size_t)n * 128);
    float acc = 0.f;
#pragma unroll
    for (int q = 0; q < 32; q++) {
      float4 s4 = sp[q];
      acc += s4.x * wr[4 * q] + s4.y * wr[4 * q + 1]
           + s4.z * wr[4 * q + 2] + s4.w * wr[4 * q + 3];
    }
    out[(size_t)n * 512 + d] = acc * 0.088388347648318447f;   // 1/sqrt(128)
  }
}

__global__ __launch_bounds__(256, 4) void k_ov(const float* __restrict__ node_agg,
        const float* __restrict__ Wv, float* __restrict__ out) {
  int t = threadIdx.x;
  int d = t & 127, sub = t >> 7;
  int sid = blockIdx.x * 2 + sub;
  float wr[64];
#pragma unroll
  for (int m = 0; m < 64; m++) wr[m] = Wv[m * 128 + d];
#pragma unroll
  for (int m = 0; m < 64; m++) PIN(wr[m]);
  for (int n = sid; n < NN; n += 4096) {
    const float4* vp = (const float4*)(node_agg + (size_t)n * 256 + 64);
    float a[3] = {0.f, 0.f, 0.f};
#pragma unroll
    for (int q = 0; q < 48; q++) {
      float4 v4 = vp[q];
      float vals[4] = {v4.x, v4.y, v4.z, v4.w};
#pragma unroll
      for (int jj = 0; jj < 4; jj++) {
        int k = 4 * q + jj;          // compile-time after unroll
        a[k % 3] += vals[jj] * wr[k / 3];
      }
    }
    float* op = out + (size_t)n * 512 + 128 + (size_t)d * 3;
    op[0] = a[0]; op[1] = a[1]; op[2] = a[2];
  }
}

extern "C" void kernel_launch(void* const* d_in, const int* in_sizes, int n_in,
                              void* d_out, int out_size, void* d_ws, size_t ws_size,
                              hipStream_t stream) {
  const float* x    = (const float*)d_in[0];
  const int*   idx_i = (const int*)d_in[1];
  const int*   idx_j = (const int*)d_in[2];
  const float* fij  = (const float*)d_in[3];
  const float* rcut = (const float*)d_in[4];
  const float* Yr   = (const float*)d_in[5];
  const float* w_s  = (const float*)d_in[6];
  const float* w_v  = (const float*)d_in[7];
  const float* W1   = (const float*)d_in[8];
  const float* b1   = (const float*)d_in[9];
  const float* W2   = (const float*)d_in[10];
  const float* b2   = (const float*)d_in[11];
  const float* w1s  = (const float*)d_in[12];
  const float* w1v  = (const float*)d_in[13];
  const float* w2s  = (const float*)d_in[14];
  const float* w2v  = (const float*)d_in[15];
  float* out = (float*)d_out;

  char* ws = (char*)d_ws;
  size_t off = 0;
  auto alloc = [&](size_t bytes) {
    void* p = ws + off;
    off += (bytes + 255) & ~(size_t)255;
    return p;
  };
  float4* hsv  = (float4*)alloc((size_t)NN * 32 * 16);
  float* hbuf  = (float*)alloc((size_t)EE * 32 * 4);
  float* nagg  = (float*)alloc((size_t)NN * 256 * 4);
  float* Wv    = (float*)alloc((size_t)8192 * 4);
  float* os1   = (float*)alloc((size_t)NN * 128 * 4);
  int* cnt     = (int*)alloc((size_t)NN * 4);
  int* offs    = (int*)alloc((size_t)(NN + 1) * 4);
  int* pos     = (int*)alloc((size_t)EE * 4);
  int* elist   = (int*)alloc((size_t)EE * 4);

  hipMemsetAsync(cnt, 0, (size_t)NN * 4, stream);
  k_count<<<EE / 256, 256, 0, stream>>>(idx_i, cnt, pos);
  k_scan<<<1, 256, 0, stream>>>(cnt, offs);
  k_fill<<<EE / 256, 256, 0, stream>>>(idx_i, pos, offs, elist);
  k_embed<<<NN * 8 / 256, 256, 0, stream>>>(x, w_s, w_v, hsv);
  k_h<<<EE / 256, 256, 0, stream>>>(fij, W1, b1, hbuf);
  k_wv<<<32, 256, 0, stream>>>(w1v, w2v, Wv);
  k_edges<<<NN / 4, 256, 0, stream>>>(hbuf, rcut, Yr, idx_j, hsv, W2, b2, offs, elist, nagg);
  k_os1<<<2048, 256, 0, stream>>>(nagg, w1s, os1);
  k_os2<<<2048, 256, 0, stream>>>(os1, w2s, out);
  k_ov<<<2048, 256, 0, stream>>>(nagg, Wv, out);
}

// Round 4
// 406.418 us; speedup vs baseline: 2.2141x; 2.2141x over previous
//
#include <hip/hip_runtime.h>
#include <math.h>

#define NN 16384
#define BB 128
#define FF 32
#define RR 20
#define EE 262144

__device__ __forceinline__ float sspf(float x) {
  // softplus(x) - log(2), numerically stable
  return fmaxf(x, 0.0f) + log1pf(expf(-fabsf(x))) - 0.69314718055994531f;
}

// Pin a float into a VGPR (defeats load-rematerialization). Only safe when the
// pinned set + live temps fits the register budget (~<=40 pinned floats).
#define PIN(v) asm volatile("" : "+v"(v))

// ---------------- K1: node embeddings hsv[n*32+f] = {hs, hvx, hvy, hvz} ----------------
__global__ __launch_bounds__(256) void k_embed(const float* __restrict__ x,
        const float* __restrict__ ws, const float* __restrict__ wv,
        float4* __restrict__ hsv) {
  int tid = blockIdx.x * 256 + threadIdx.x;   // N*8 threads
  int n = tid >> 3, fq = tid & 7;
  const float* xr = x + (size_t)n * 512;
  float acc[4][4];
#pragma unroll
  for (int k = 0; k < 4; k++)
#pragma unroll
    for (int c = 0; c < 4; c++) acc[k][c] = 0.f;
  for (int bq = 0; bq < 32; bq++) {
    float4 xs4 = *(const float4*)(xr + 4 * bq);
    float4 a0 = *(const float4*)(xr + 128 + 12 * bq);
    float4 a1 = *(const float4*)(xr + 128 + 12 * bq + 4);
    float4 a2 = *(const float4*)(xr + 128 + 12 * bq + 8);
    float xsv[4] = {xs4.x, xs4.y, xs4.z, xs4.w};
    float vv[4][3];
    vv[0][0] = a0.x; vv[0][1] = a0.y; vv[0][2] = a0.z;
    vv[1][0] = a0.w; vv[1][1] = a1.x; vv[1][2] = a1.y;
    vv[2][0] = a1.z; vv[2][1] = a1.w; vv[2][2] = a2.x;
    vv[3][0] = a2.y; vv[3][1] = a2.z; vv[3][2] = a2.w;
#pragma unroll
    for (int bb = 0; bb < 4; bb++) {
      int b = 4 * bq + bb;
      float4 w_s = *(const float4*)(ws + b * 32 + 4 * fq);
      float4 w_v = *(const float4*)(wv + b * 32 + 4 * fq);
      float wsx[4] = {w_s.x, w_s.y, w_s.z, w_s.w};
      float wvx[4] = {w_v.x, w_v.y, w_v.z, w_v.w};
#pragma unroll
      for (int k = 0; k < 4; k++) {
        acc[k][0] += xsv[bb] * wsx[k];
        acc[k][1] += vv[bb][0] * wvx[k];
        acc[k][2] += vv[bb][1] * wvx[k];
        acc[k][3] += vv[bb][2] * wvx[k];
      }
    }
  }
  const float sc = 0.088388347648318447f;  // 1/sqrt(128)
#pragma unroll
  for (int k = 0; k < 4; k++) {
    float4 o;
    o.x = acc[k][0] * sc; o.y = acc[k][1] * sc;
    o.z = acc[k][2] * sc; o.w = acc[k][3] * sc;
    hsv[(size_t)n * 32 + 4 * fq + k] = o;
  }
}

// ---------------- CSR build ----------------
__global__ __launch_bounds__(256) void k_count(const int* __restrict__ idx_i,
        int* __restrict__ cnt, int* __restrict__ pos) {
  int e = blockIdx.x * 256 + threadIdx.x;
  pos[e] = atomicAdd(cnt + idx_i[e], 1);
}

__global__ __launch_bounds__(256) void k_scan(const int* __restrict__ cnt,
        int* __restrict__ offs) {
  __shared__ int part[256];
  int t = threadIdx.x;
  int s = 0;
  for (int i = t * 64; i < t * 64 + 64; ++i) s += cnt[i];
  part[t] = s;
  __syncthreads();
  if (t == 0) {
    int run = 0;
    for (int i = 0; i < 256; i++) { int v = part[i]; part[i] = run; run += v; }
    offs[NN] = run;
  }
  __syncthreads();
  int run = part[t];
  for (int i = t * 64; i < t * 64 + 64; ++i) { offs[i] = run; run += cnt[i]; }
}

__global__ __launch_bounds__(256) void k_fill(const int* __restrict__ idx_i,
        const int* __restrict__ pos, const int* __restrict__ offs,
        int* __restrict__ elist) {
  int e = blockIdx.x * 256 + threadIdx.x;
  elist[offs[idx_i[e]] + pos[e]] = e;
}

// ---------------- KA: per-edge filter MLP first layer: h = ssp(f_ij @ W1 + b1) ----------------
__global__ __launch_bounds__(256) void k_h(const float* __restrict__ fij,
        const float* __restrict__ W1, const float* __restrict__ b1,
        float* __restrict__ hout) {
  __shared__ float sfij[20 * 256];   // [r][edge_local]
  __shared__ float sW1[640];
  __shared__ float sb1[32];
  int t = threadIdx.x;
  int e0 = blockIdx.x * 256;
  for (int i = t; i < 5120; i += 256) {
    float v = fij[(size_t)e0 * 20 + i];
    int el = i / 20, r = i - el * 20;
    sfij[r * 256 + el] = v;
  }
  for (int i = t; i < 640; i += 256) sW1[i] = W1[i];
  if (t < 32) sb1[t] = b1[t];
  __syncthreads();
  int fq = t & 3, el = t >> 2;   // el 0..63 (4 edges each), fq 0..3 (8 fp each)
  int fp0 = fq * 8;
  float acc[4][8];
#pragma unroll
  for (int j = 0; j < 4; j++)
#pragma unroll
    for (int i = 0; i < 8; i++) acc[j][i] = sb1[fp0 + i];
#pragma unroll
  for (int r = 0; r < 20; r++) {
    float4 fe4 = *(const float4*)(sfij + r * 256 + el * 4);
    float fe[4] = {fe4.x, fe4.y, fe4.z, fe4.w};
    float4 wA = *(const float4*)(sW1 + r * 32 + fp0);
    float4 wB = *(const float4*)(sW1 + r * 32 + fp0 + 4);
    float w[8] = {wA.x, wA.y, wA.z, wA.w, wB.x, wB.y, wB.z, wB.w};
#pragma unroll
    for (int j = 0; j < 4; j++)
#pragma unroll
      for (int i = 0; i < 8; i++) acc[j][i] += fe[j] * w[i];
  }
#pragma unroll
  for (int j = 0; j < 4; j++) {
    float4 o1, o2;
    o1.x = sspf(acc[j][0]); o1.y = sspf(acc[j][1]);
    o1.z = sspf(acc[j][2]); o1.w = sspf(acc[j][3]);
    o2.x = sspf(acc[j][4]); o2.y = sspf(acc[j][5]);
    o2.z = sspf(acc[j][6]); o2.w = sspf(acc[j][7]);
    size_t base = ((size_t)(e0 + el * 4 + j)) * 32 + fp0;
    *(float4*)(hout + base) = o1;
    *(float4*)(hout + base + 4) = o2;
  }
}

// ---------------- fused vector output weight: Wv = w1v @ w2v * 1/sqrt(64*128) ----------------
__global__ __launch_bounds__(256) void k_wv(const float* __restrict__ w1v,
        const float* __restrict__ w2v, float* __restrict__ Wv) {
  int o = blockIdx.x * 256 + threadIdx.x;   // 8192
  int m = o >> 7, d = o & 127;
  float s = 0.f;
  for (int b = 0; b < 128; b++) s += w1v[m * 128 + b] * w2v[b * 128 + d];
  Wv[o] = s * 0.011048543456039804f;
}

// ---------------- KB: per-edge W2 GEMV + geometric features + CSR aggregation ----------------
// ONE COLUMN PER LANE: wave-pair covers the 128 used W2 columns; each pair owns
// one node's edge list. 32 pinned weights/lane (~60 VGPR total -> fits the
// 64-VGPR/8-wave occupancy step). No LDS, no barriers, no cross-lane reduce.
__global__ __launch_bounds__(256, 4) void k_edges(
        const float* __restrict__ h, const float* __restrict__ rcut,
        const float* __restrict__ Yr, const int* __restrict__ idxj,
        const float4* __restrict__ hsv,
        const float* __restrict__ W2, const float* __restrict__ b2,
        const int* __restrict__ offs, const int* __restrict__ elist,
        float* __restrict__ node_agg) {
  int t = threadIdx.x;
  int w = t >> 6, l = t & 63;
  int pair = w >> 1, hw = w & 1;
  int fl = l >> 2, k = l & 3;
  int f = hw * 16 + fl;            // 0..31
  int col = 6 * f + k;             // used W2 column
  int n = blockIdx.x * 2 + pair;   // 8192 blocks, one node per wave-pair
  float wreg[32];
#pragma unroll
  for (int fp = 0; fp < 32; fp++) wreg[fp] = W2[fp * 192 + col];
#pragma unroll
  for (int fp = 0; fp < 32; fp++) PIN(wreg[fp]);
  float bcol = b2[col];
  int start = offs[n], end = offs[n + 1];
  float acc0 = 0.f, acc1 = 0.f, acc2 = 0.f;
  bool k2 = (k == 2);
  for (int ei = start; ei < end; ++ei) {
    int e = elist[ei];
    int j = idxj[e];
    float rc = rcut[e];
    float4 y4 = *(const float4*)(Yr + (size_t)e * 4);
    float ys = y4.x, yx = y4.y, yy = y4.z, yz = y4.w;
    float4 sv = hsv[(size_t)j * 32 + f];
    float s = sv.x, vx = sv.y, vy = sv.z, vz = sv.w;
    const float4* hp = (const float4*)(h + (size_t)e * 32);
    float d0 = 0.f;
#pragma unroll
    for (int q = 0; q < 8; q++) {
      float4 h4 = hp[q];
      d0 += h4.x * wreg[4 * q] + h4.y * wreg[4 * q + 1]
          + h4.z * wreg[4 * q + 2] + h4.w * wreg[4 * q + 3];
    }
    float W = (d0 + bcol) * rc;
    float dv = (vx * yx + vy * yy + vz * yz) * 0.57735026918962576f; // IS3
    // branchless per-k geometric factor (m1/m2 garbage for k<2: never stored)
    float m0 = (k == 0) ? s * ys : (k == 1) ? dv : k2 ? s * yx : vx * ys;
    float m1 = k2 ? s * yy : vy * ys;
    float m2 = k2 ? s * yz : vz * ys;
    acc0 += m0 * W; acc1 += m1 * W; acc2 += m2 * W;
  }
  float* na = node_agg + (size_t)n * 256;
  if (k == 0)      na[f] = acc0;                       // ch0 -> s_in[0:32]
  else if (k == 1) na[32 + f] = acc0;                  // ch1 -> s_in[32:64]
  else if (k == 2) {                                   // t_v1 -> v_in m=f
    na[64 + 3 * f + 0] = acc0; na[64 + 3 * f + 1] = acc1; na[64 + 3 * f + 2] = acc2;
  } else {                                             // t_v2 -> v_in m=32+f
    na[160 + 3 * f + 0] = acc0; na[160 + 3 * f + 1] = acc1; na[160 + 3 * f + 2] = acc2;
  }
}

// ---------------- output transforms: weights in LDS, 4-node batch per thread ----------------
__global__ __launch_bounds__(256) void k_os1(const float* __restrict__ na,
        const float* __restrict__ w1s, float* __restrict__ os1) {
  __shared__ float sw[8192];       // w1s 64x128, natural [m][d] layout
  int t = threadIdx.x;
  for (int i = t; i < 8192; i += 256) sw[i] = w1s[i];
  __syncthreads();
  int d = t & 127, g = t >> 7;
  int nb = blockIdx.x * 8 + g * 4;          // 2048 blocks, 8 nodes/block
  const float* r0 = na + (size_t)nb * 256;
  const float* r1 = r0 + 256;
  const float* r2 = r1 + 256;
  const float* r3 = r2 + 256;
  float a0 = 0.f, a1 = 0.f, a2 = 0.f, a3 = 0.f;
#pragma unroll
  for (int mq = 0; mq < 16; mq++) {
    float w0 = sw[(4 * mq + 0) * 128 + d];
    float w1 = sw[(4 * mq + 1) * 128 + d];
    float w2 = sw[(4 * mq + 2) * 128 + d];
    float w3 = sw[(4 * mq + 3) * 128 + d];
    float4 x0 = *(const float4*)(r0 + 4 * mq);
    float4 x1 = *(const float4*)(r1 + 4 * mq);
    float4 x2 = *(const float4*)(r2 + 4 * mq);
    float4 x3 = *(const float4*)(r3 + 4 * mq);
    a0 += x0.x * w0 + x0.y * w1 + x0.z * w2 + x0.w * w3;
    a1 += x1.x * w0 + x1.y * w1 + x1.z * w2 + x1.w * w3;
    a2 += x2.x * w0 + x2.y * w1 + x2.z * w2 + x2.w * w3;
    a3 += x3.x * w0 + x3.y * w1 + x3.z * w2 + x3.w * w3;
  }
  os1[(size_t)(nb + 0) * 128 + d] = sspf(a0 * 0.125f);   // 1/sqrt(64)
  os1[(size_t)(nb + 1) * 128 + d] = sspf(a1 * 0.125f);
  os1[(size_t)(nb + 2) * 128 + d] = sspf(a2 * 0.125f);
  os1[(size_t)(nb + 3) * 128 + d] = sspf(a3 * 0.125f);
}

__global__ __launch_bounds__(256) void k_os2(const float* __restrict__ os1,
        const float* __restrict__ w2s, float* __restrict__ out) {
  __shared__ float sw[16384];      // w2s 128x128 = 64 KB
  int t = threadIdx.x;
  for (int i = t; i < 16384; i += 256) sw[i] = w2s[i];
  __syncthreads();
  int d = t & 127, g = t >> 7;
  int nb = blockIdx.x * 8 + g * 4;          // 2048 blocks
  const float* r0 = os1 + (size_t)nb * 128;
  const float* r1 = r0 + 128;
  const float* r2 = r1 + 128;
  const float* r3 = r2 + 128;
  float a0 = 0.f, a1 = 0.f, a2 = 0.f, a3 = 0.f;
#pragma unroll
  for (int mq = 0; mq < 32; mq++) {
    float w0 = sw[(4 * mq + 0) * 128 + d];
    float w1 = sw[(4 * mq + 1) * 128 + d];
    float w2 = sw[(4 * mq + 2) * 128 + d];
    float w3 = sw[(4 * mq + 3) * 128 + d];
    float4 x0 = *(const float4*)(r0 + 4 * mq);
    float4 x1 = *(const float4*)(r1 + 4 * mq);
    float4 x2 = *(const float4*)(r2 + 4 * mq);
    float4 x3 = *(const float4*)(r3 + 4 * mq);
    a0 += x0.x * w0 + x0.y * w1 + x0.z * w2 + x0.w * w3;
    a1 += x1.x * w0 + x1.y * w1 + x1.z * w2 + x1.w * w3;
    a2 += x2.x * w0 + x2.y * w1 + x2.z * w2 + x2.w * w3;
    a3 += x3.x * w0 + x3.y * w1 + x3.z * w2 + x3.w * w3;
  }
  const float sc = 0.088388347648318447f;   // 1/sqrt(128)
  out[(size_t)(nb + 0) * 512 + d] = a0 * sc;
  out[(size_t)(nb + 1) * 512 + d] = a1 * sc;
  out[(size_t)(nb + 2) * 512 + d] = a2 * sc;
  out[(size_t)(nb + 3) * 512 + d] = a3 * sc;
}

__global__ __launch_bounds__(256) void k_ov(const float* __restrict__ na,
        const float* __restrict__ Wv, float* __restrict__ out) {
  __shared__ float sw[8192];       // Wv 64x128
  int t = threadIdx.x;
  for (int i = t; i < 8192; i += 256) sw[i] = Wv[i];
  __syncthreads();
  int d = t & 127, g = t >> 7;
  int nb = blockIdx.x * 4 + g * 2;          // 4096 blocks, 4 nodes/block
  const float* r0 = na + (size_t)nb * 256 + 64;   // v_in row: 192 floats
  const float* r1 = r0 + 256;
  float a00 = 0.f, a01 = 0.f, a02 = 0.f, a10 = 0.f, a11 = 0.f, a12 = 0.f;
#pragma unroll
  for (int mq = 0; mq < 16; mq++) {
    float w0 = sw[(4 * mq + 0) * 128 + d];
    float w1 = sw[(4 * mq + 1) * 128 + d];
    float w2 = sw[(4 * mq + 2) * 128 + d];
    float w3 = sw[(4 * mq + 3) * 128 + d];
    float4 p0 = *(const float4*)(r0 + 12 * mq);
    float4 p1 = *(const float4*)(r0 + 12 * mq + 4);
    float4 p2 = *(const float4*)(r0 + 12 * mq + 8);
    a00 += p0.x * w0 + p0.w * w1 + p1.z * w2 + p2.y * w3;
    a01 += p0.y * w0 + p1.x * w1 + p1.w * w2 + p2.z * w3;
    a02 += p0.z * w0 + p1.y * w1 + p2.x * w2 + p2.w * w3;
    float4 q0 = *(const float4*)(r1 + 12 * mq);
    float4 q1 = *(const float4*)(r1 + 12 * mq + 4);
    float4 q2 = *(const float4*)(r1 + 12 * mq + 8);
    a10 += q0.x * w0 + q0.w * w1 + q1.z * w2 + q2.y * w3;
    a11 += q0.y * w0 + q1.x * w1 + q1.w * w2 + q2.z * w3;
    a12 += q0.z * w0 + q1.y * w1 + q2.x * w2 + q2.w * w3;
  }
  float* o0 = out + (size_t)(nb + 0) * 512 + 128 + 3 * d;
  o0[0] = a00; o0[1] = a01; o0[2] = a02;
  float* o1 = out + (size_t)(nb + 1) * 512 + 128 + 3 * d;
  o1[0] = a10; o1[1] = a11; o1[2] = a12;
}

extern "C" void kernel_launch(void* const* d_in, const int* in_sizes, int n_in,
                              void* d_out, int out_size, void* d_ws, size_t ws_size,
                              hipStream_t stream) {
  const float* x    = (const float*)d_in[0];
  const int*   idx_i = (const int*)d_in[1];
  const int*   idx_j = (const int*)d_in[2];
  const float* fij  = (const float*)d_in[3];
  const float* rcut = (const float*)d_in[4];
  const float* Yr   = (const float*)d_in[5];
  const float* w_s  = (const float*)d_in[6];
  const float* w_v  = (const float*)d_in[7];
  const float* W1   = (const float*)d_in[8];
  const float* b1   = (const float*)d_in[9];
  const float* W2   = (const float*)d_in[10];
  const float* b2   = (const float*)d_in[11];
  const float* w1s  = (const float*)d_in[12];
  const float* w1v  = (const float*)d_in[13];
  const float* w2s  = (const float*)d_in[14];
  const float* w2v  = (const float*)d_in[15];
  float* out = (float*)d_out;

  char* ws = (char*)d_ws;
  size_t off = 0;
  auto alloc = [&](size_t bytes) {
    void* p = ws + off;
    off += (bytes + 255) & ~(size_t)255;
    return p;
  };
  float4* hsv  = (float4*)alloc((size_t)NN * 32 * 16);
  float* hbuf  = (float*)alloc((size_t)EE * 32 * 4);
  float* nagg  = (float*)alloc((size_t)NN * 256 * 4);
  float* Wv    = (float*)alloc((size_t)8192 * 4);
  float* os1   = (float*)alloc((size_t)NN * 128 * 4);
  int* cnt     = (int*)alloc((size_t)NN * 4);
  int* offs    = (int*)alloc((size_t)(NN + 1) * 4);
  int* pos     = (int*)alloc((size_t)EE * 4);
  int* elist   = (int*)alloc((size_t)EE * 4);

  hipMemsetAsync(cnt, 0, (size_t)NN * 4, stream);
  k_count<<<EE / 256, 256, 0, stream>>>(idx_i, cnt, pos);
  k_scan<<<1, 256, 0, stream>>>(cnt, offs);
  k_fill<<<EE / 256, 256, 0, stream>>>(idx_i, pos, offs, elist);
  k_embed<<<NN * 8 / 256, 256, 0, stream>>>(x, w_s, w_v, hsv);
  k_h<<<EE / 256, 256, 0, stream>>>(fij, W1, b1, hbuf);
  k_wv<<<32, 256, 0, stream>>>(w1v, w2v, Wv);
  k_edges<<<NN / 2, 256, 0, stream>>>(hbuf, rcut, Yr, idx_j, hsv, W2, b2, offs, elist, nagg);
  k_os1<<<NN / 8, 256, 0, stream>>>(nagg, w1s, os1);
  k_os2<<<NN / 8, 256, 0, stream>>>(os1, w2s, out);
  k_ov<<<NN / 4, 256, 0, stream>>>(nagg, Wv, out);
}

// Round 5
// 361.326 us; speedup vs baseline: 2.4904x; 1.1248x over previous
//
#include <hip/hip_runtime.h>
#include <math.h>

#define NN 16384
#define BB 128
#define FF 32
#define RR 20
#define EE 262144
#define NCH 4
#define CHE (EE / NCH)

__device__ __forceinline__ float sspf(float x) {
  // softplus(x) - log(2), numerically stable
  return fmaxf(x, 0.0f) + log1pf(expf(-fabsf(x))) - 0.69314718055994531f;
}

// ---------------- K1: node embeddings hsv[n*32+f] = {hs, hvx, hvy, hvz} ----------------
__global__ __launch_bounds__(256) void k_embed(const float* __restrict__ x,
        const float* __restrict__ ws, const float* __restrict__ wv,
        float4* __restrict__ hsv) {
  int tid = blockIdx.x * 256 + threadIdx.x;   // N*8 threads
  int n = tid >> 3, fq = tid & 7;
  const float* xr = x + (size_t)n * 512;
  float acc[4][4];
#pragma unroll
  for (int k = 0; k < 4; k++)
#pragma unroll
    for (int c = 0; c < 4; c++) acc[k][c] = 0.f;
  for (int bq = 0; bq < 32; bq++) {
    float4 xs4 = *(const float4*)(xr + 4 * bq);
    float4 a0 = *(const float4*)(xr + 128 + 12 * bq);
    float4 a1 = *(const float4*)(xr + 128 + 12 * bq + 4);
    float4 a2 = *(const float4*)(xr + 128 + 12 * bq + 8);
    float xsv[4] = {xs4.x, xs4.y, xs4.z, xs4.w};
    float vv[4][3];
    vv[0][0] = a0.x; vv[0][1] = a0.y; vv[0][2] = a0.z;
    vv[1][0] = a0.w; vv[1][1] = a1.x; vv[1][2] = a1.y;
    vv[2][0] = a1.z; vv[2][1] = a1.w; vv[2][2] = a2.x;
    vv[3][0] = a2.y; vv[3][1] = a2.z; vv[3][2] = a2.w;
#pragma unroll
    for (int bb = 0; bb < 4; bb++) {
      int b = 4 * bq + bb;
      float4 w_s = *(const float4*)(ws + b * 32 + 4 * fq);
      float4 w_v = *(const float4*)(wv + b * 32 + 4 * fq);
      float wsx[4] = {w_s.x, w_s.y, w_s.z, w_s.w};
      float wvx[4] = {w_v.x, w_v.y, w_v.z, w_v.w};
#pragma unroll
      for (int k = 0; k < 4; k++) {
        acc[k][0] += xsv[bb] * wsx[k];
        acc[k][1] += vv[bb][0] * wvx[k];
        acc[k][2] += vv[bb][1] * wvx[k];
        acc[k][3] += vv[bb][2] * wvx[k];
      }
    }
  }
  const float sc = 0.088388347648318447f;  // 1/sqrt(128)
#pragma unroll
  for (int k = 0; k < 4; k++) {
    float4 o;
    o.x = acc[k][0] * sc; o.y = acc[k][1] * sc;
    o.z = acc[k][2] * sc; o.w = acc[k][3] * sc;
    hsv[(size_t)n * 32 + 4 * fq + k] = o;
  }
}

// ---------------- CSR build ----------------
__global__ __launch_bounds__(256) void k_count(const int* __restrict__ idx_i,
        int* __restrict__ cnt, int* __restrict__ pos) {
  int e = blockIdx.x * 256 + threadIdx.x;
  pos[e] = atomicAdd(cnt + idx_i[e], 1);
}

__global__ __launch_bounds__(256) void k_scan(const int* __restrict__ cnt,
        int* __restrict__ offs) {
  __shared__ int part[256];
  int t = threadIdx.x;
  int s = 0;
  for (int i = t * 64; i < t * 64 + 64; ++i) s += cnt[i];
  part[t] = s;
  __syncthreads();
  if (t == 0) {
    int run = 0;
    for (int i = 0; i < 256; i++) { int v = part[i]; part[i] = run; run += v; }
    offs[NN] = run;
  }
  __syncthreads();
  int run = part[t];
  for (int i = t * 64; i < t * 64 + 64; ++i) { offs[i] = run; run += cnt[i]; }
}

// also permutes idx_j and Yr into CSR order so k_agg streams them sequentially
__global__ __launch_bounds__(256) void k_fill(const int* __restrict__ idx_i,
        const int* __restrict__ idx_j, const float* __restrict__ Yr,
        const int* __restrict__ pos, const int* __restrict__ offs,
        int* __restrict__ elist, int* __restrict__ idxj_csr,
        float4* __restrict__ Yr_csr) {
  int e = blockIdx.x * 256 + threadIdx.x;
  int slot = offs[idx_i[e]] + pos[e];
  elist[slot] = e;
  idxj_csr[slot] = idx_j[e];
  Yr_csr[slot] = *(const float4*)(Yr + (size_t)e * 4);
}

// ---------------- fused vector output weight: Wv = w1v @ w2v * 1/sqrt(64*128) ----------------
__global__ __launch_bounds__(256) void k_wv(const float* __restrict__ w1v,
        const float* __restrict__ w2v, float* __restrict__ Wv) {
  int o = blockIdx.x * 256 + threadIdx.x;   // 8192
  int m = o >> 7, d = o & 127;
  float s = 0.f;
  for (int b = 0; b < 128; b++) s += w1v[m * 128 + b] * w2v[b * 128 + d];
  Wv[o] = s * 0.011048543456039804f;
}

// ---------------- k_wab: CSR-slot-major fused filter MLP ----------------
// Per 64-slot tile: gather fij rows, h = ssp(fij@W1+b1) in LDS, dense fp32
// GEMM h @ W2c (128 used cols) + b2, *rcut, coalesced CSR-order write.
__global__ __launch_bounds__(256) void k_wab(
        const float* __restrict__ fij, const float* __restrict__ rcut,
        const int* __restrict__ elist,
        const float* __restrict__ W1, const float* __restrict__ b1,
        const float* __restrict__ W2, const float* __restrict__ b2,
        float* __restrict__ Wab, int c0) {
  __shared__ int selist[64];
  __shared__ float sW1[640];
  __shared__ float sb1[32];
  __shared__ float sW2c[4096];     // [p][128] compact used cols (4f+k <- 6f+k)
  __shared__ float sb2c[128];
  __shared__ float sfij[20 * 66];  // [r][el], pad 66
  __shared__ float sh[64 * 36];    // [el][fp], pad 36 (16B-aligned rows)
  __shared__ float srct[64];
  int t = threadIdx.x;
  int s0 = c0 + blockIdx.x * 64;
  if (t < 64) selist[t] = elist[s0 + t];
  for (int i = t; i < 640; i += 256) sW1[i] = W1[i];
  if (t < 32) sb1[t] = b1[t];
  for (int i = t; i < 4096; i += 256) {
    int p = i >> 7, c = i & 127;
    sW2c[i] = W2[p * 192 + 6 * (c >> 2) + (c & 3)];
  }
  if (t < 128) sb2c[t] = b2[6 * (t >> 2) + (t & 3)];
  __syncthreads();
  for (int i = t; i < 1280; i += 256) {
    int row = i / 20, col = i - row * 20;
    sfij[col * 66 + row] = fij[(size_t)selist[row] * 20 + col];
  }
  if (t < 64) srct[t] = rcut[selist[t]];
  __syncthreads();
  {
    int el = t & 63, fp0 = (t >> 6) * 8;
    float acc[8];
#pragma unroll
    for (int i = 0; i < 8; i++) acc[i] = sb1[fp0 + i];
#pragma unroll
    for (int r = 0; r < 20; r++) {
      float fe = sfij[r * 66 + el];
      float4 wA = *(const float4*)(sW1 + r * 32 + fp0);
      float4 wB = *(const float4*)(sW1 + r * 32 + fp0 + 4);
      acc[0] += fe * wA.x; acc[1] += fe * wA.y;
      acc[2] += fe * wA.z; acc[3] += fe * wA.w;
      acc[4] += fe * wB.x; acc[5] += fe * wB.y;
      acc[6] += fe * wB.z; acc[7] += fe * wB.w;
    }
#pragma unroll
    for (int i = 0; i < 8; i++) sh[el * 36 + fp0 + i] = sspf(acc[i]);
  }
  __syncthreads();
  {
    int eq = t >> 4, cq = (t & 15) * 8;   // 4 edges x 8 cols per thread
    float acc[4][8];
#pragma unroll
    for (int j = 0; j < 4; j++)
#pragma unroll
      for (int i = 0; i < 8; i++) acc[j][i] = sb2c[cq + i];
#pragma unroll
    for (int p = 0; p < 32; p++) {
      float4 wA = *(const float4*)(sW2c + p * 128 + cq);
      float4 wB = *(const float4*)(sW2c + p * 128 + cq + 4);
      float w[8] = {wA.x, wA.y, wA.z, wA.w, wB.x, wB.y, wB.z, wB.w};
#pragma unroll
      for (int j = 0; j < 4; j++) {
        float hh = sh[(4 * eq + j) * 36 + p];
#pragma unroll
        for (int i = 0; i < 8; i++) acc[j][i] += hh * w[i];
      }
    }
#pragma unroll
    for (int j = 0; j < 4; j++) {
      float rc = srct[4 * eq + j];
      float* base = Wab + (size_t)(blockIdx.x * 64 + 4 * eq + j) * 128 + cq;
      float4 o1, o2;
      o1.x = acc[j][0] * rc; o1.y = acc[j][1] * rc;
      o1.z = acc[j][2] * rc; o1.w = acc[j][3] * rc;
      o2.x = acc[j][4] * rc; o2.y = acc[j][5] * rc;
      o2.z = acc[j][6] * rc; o2.w = acc[j][7] * rc;
      *(float4*)base = o1;
      *(float4*)(base + 4) = o2;
    }
  }
}

// ---------------- k_agg: one wave per node; sequential CSR streams ----------------
// lane l: f = l&31, kh = l>>5 -> cols {4f+2kh, 4f+2kh+1}. Only random access is
// hsv[j] (prefetched 1 ahead; j fetched 2 ahead).
__global__ __launch_bounds__(256) void k_agg(
        const float2* __restrict__ Wab2, const float4* __restrict__ Yr_csr,
        const int* __restrict__ idxj_csr, const float4* __restrict__ hsv,
        const int* __restrict__ offs, float* __restrict__ nagg,
        int c0, int c1) {
  int t = threadIdx.x;
  int n = blockIdx.x * 4 + (t >> 6);
  int l = t & 63, f = l & 31, kh = l >> 5;
  int start = offs[n], end = offs[n + 1];
  int s = start > c0 ? start : c0;
  int eend = end < c1 ? end : c1;
  if (s >= eend) return;    // wave-uniform exit
  float a0 = 0, a1 = 0, a2 = 0, a3 = 0, a4 = 0, a5 = 0;
  int w2i = 2 * f + kh;
  // prologue: cur = slot s; j for s+1 prefetched
  int j = idxj_csr[s];
  float4 y = Yr_csr[s];
  float2 d = Wab2[(size_t)(s - c0) * 64 + w2i];
  float4 sv = hsv[(size_t)j * 32 + f];
  int last = eend - 1;
  int i1 = s + 1 < last ? s + 1 : last;
  int j2 = idxj_csr[i1];
  for (int ei = s; ei < eend; ++ei) {
    int in1 = ei + 1 < last ? ei + 1 : last;   // next slot (clamped)
    int in2 = ei + 2 < last ? ei + 2 : last;   // next-next (clamped)
    float4 svn = hsv[(size_t)j2 * 32 + f];     // j2 already resident
    float4 yn = Yr_csr[in1];
    float2 dn = Wab2[(size_t)(in1 - c0) * 64 + w2i];
    int j3 = idxj_csr[in2];
    float ys = y.x, yx = y.y, yy = y.z, yz = y.w;
    float ss = sv.x, vx = sv.y, vy = sv.z, vz = sv.w;
    if (kh == 0) {
      a0 += ss * ys * d.x;
      a1 += (vx * yx + vy * yy + vz * yz) * 0.57735026918962576f * d.y;
    } else {
      a0 += ss * yx * d.x; a1 += ss * yy * d.x; a2 += ss * yz * d.x;
      a3 += vx * ys * d.y; a4 += vy * ys * d.y; a5 += vz * ys * d.y;
    }
    y = yn; d = dn; sv = svn; j2 = j3;
  }
  float* na = nagg + (size_t)n * 256;
  if (kh == 0) {
    na[f] += a0;
    na[32 + f] += a1;
  } else {
    na[64 + 3 * f + 0] += a0;  na[64 + 3 * f + 1] += a1;  na[64 + 3 * f + 2] += a2;
    na[160 + 3 * f + 0] += a3; na[160 + 3 * f + 1] += a4; na[160 + 3 * f + 2] += a5;
  }
}

// ---------------- output transforms: weights in LDS, 8-node batch per thread ----------------
__global__ __launch_bounds__(256) void k_os1(const float* __restrict__ na,
        const float* __restrict__ w1s, float* __restrict__ os1) {
  __shared__ float sw[8192];       // w1s 64x128, [m][d]
  int t = threadIdx.x;
  for (int i = t; i < 8192; i += 256) sw[i] = w1s[i];
  __syncthreads();
  int d = t & 127, g = t >> 7;
  int nb = blockIdx.x * 16 + g * 8;         // 1024 blocks, 16 nodes/block
  const float* rb = na + (size_t)nb * 256;
  float a[8] = {0, 0, 0, 0, 0, 0, 0, 0};
#pragma unroll
  for (int mq = 0; mq < 16; mq++) {
    float w0 = sw[(4 * mq + 0) * 128 + d];
    float w1 = sw[(4 * mq + 1) * 128 + d];
    float w2 = sw[(4 * mq + 2) * 128 + d];
    float w3 = sw[(4 * mq + 3) * 128 + d];
#pragma unroll
    for (int u = 0; u < 8; u++) {
      float4 x4 = *(const float4*)(rb + u * 256 + 4 * mq);
      a[u] += x4.x * w0 + x4.y * w1 + x4.z * w2 + x4.w * w3;
    }
  }
#pragma unroll
  for (int u = 0; u < 8; u++)
    os1[(size_t)(nb + u) * 128 + d] = sspf(a[u] * 0.125f);   // 1/sqrt(64)
}

__global__ __launch_bounds__(256) void k_os2(const float* __restrict__ os1,
        const float* __restrict__ w2s, float* __restrict__ out) {
  __shared__ float sw[16384];      // w2s 128x128 = 64 KB
  int t = threadIdx.x;
  for (int i = t; i < 16384; i += 256) sw[i] = w2s[i];
  __syncthreads();
  int d = t & 127, g = t >> 7;
  int nb = blockIdx.x * 16 + g * 8;
  const float* rb = os1 + (size_t)nb * 128;
  float a[8] = {0, 0, 0, 0, 0, 0, 0, 0};
#pragma unroll
  for (int mq = 0; mq < 32; mq++) {
    float w0 = sw[(4 * mq + 0) * 128 + d];
    float w1 = sw[(4 * mq + 1) * 128 + d];
    float w2 = sw[(4 * mq + 2) * 128 + d];
    float w3 = sw[(4 * mq + 3) * 128 + d];
#pragma unroll
    for (int u = 0; u < 8; u++) {
      float4 x4 = *(const float4*)(rb + u * 128 + 4 * mq);
      a[u] += x4.x * w0 + x4.y * w1 + x4.z * w2 + x4.w * w3;
    }
  }
  const float sc = 0.088388347648318447f;   // 1/sqrt(128)
#pragma unroll
  for (int u = 0; u < 8; u++)
    out[(size_t)(nb + u) * 512 + d] = a[u] * sc;
}

__global__ __launch_bounds__(256) void k_ov(const float* __restrict__ na,
        const float* __restrict__ Wv, float* __restrict__ out) {
  __shared__ float sw[8192];       // Wv 64x128
  int t = threadIdx.x;
  for (int i = t; i < 8192; i += 256) sw[i] = Wv[i];
  __syncthreads();
  int d = t & 127, g = t >> 7;
  int nb = blockIdx.x * 16 + g * 8;
  const float* rb = na + (size_t)nb * 256 + 64;   // v_in rows: 192 floats
  float a[8][3];
#pragma unroll
  for (int u = 0; u < 8; u++) { a[u][0] = 0.f; a[u][1] = 0.f; a[u][2] = 0.f; }
#pragma unroll
  for (int mq = 0; mq < 16; mq++) {
    float w0 = sw[(4 * mq + 0) * 128 + d];
    float w1 = sw[(4 * mq + 1) * 128 + d];
    float w2 = sw[(4 * mq + 2) * 128 + d];
    float w3 = sw[(4 * mq + 3) * 128 + d];
#pragma unroll
    for (int u = 0; u < 8; u++) {
      const float* r = rb + u * 256 + 12 * mq;
      float4 p0 = *(const float4*)(r);
      float4 p1 = *(const float4*)(r + 4);
      float4 p2 = *(const float4*)(r + 8);
      a[u][0] += p0.x * w0 + p0.w * w1 + p1.z * w2 + p2.y * w3;
      a[u][1] += p0.y * w0 + p1.x * w1 + p1.w * w2 + p2.z * w3;
      a[u][2] += p0.z * w0 + p1.y * w1 + p2.x * w2 + p2.w * w3;
    }
  }
#pragma unroll
  for (int u = 0; u < 8; u++) {
    float* op = out + (size_t)(nb + u) * 512 + 128 + 3 * d;
    op[0] = a[u][0]; op[1] = a[u][1]; op[2] = a[u][2];
  }
}

extern "C" void kernel_launch(void* const* d_in, const int* in_sizes, int n_in,
                              void* d_out, int out_size, void* d_ws, size_t ws_size,
                              hipStream_t stream) {
  const float* x    = (const float*)d_in[0];
  const int*   idx_i = (const int*)d_in[1];
  const int*   idx_j = (const int*)d_in[2];
  const float* fij  = (const float*)d_in[3];
  const float* rcut = (const float*)d_in[4];
  const float* Yr   = (const float*)d_in[5];
  const float* w_s  = (const float*)d_in[6];
  const float* w_v  = (const float*)d_in[7];
  const float* W1   = (const float*)d_in[8];
  const float* b1   = (const float*)d_in[9];
  const float* W2   = (const float*)d_in[10];
  const float* b2   = (const float*)d_in[11];
  const float* w1s  = (const float*)d_in[12];
  const float* w1v  = (const float*)d_in[13];
  const float* w2s  = (const float*)d_in[14];
  const float* w2v  = (const float*)d_in[15];
  float* out = (float*)d_out;

  char* ws = (char*)d_ws;
  size_t off = 0;
  auto alloc = [&](size_t bytes) {
    void* p = ws + off;
    off += (bytes + 255) & ~(size_t)255;
    return p;
  };
  float4* hsv   = (float4*)alloc((size_t)NN * 32 * 16);
  float*  nagg  = (float*)alloc((size_t)NN * 256 * 4);
  float*  Wab   = (float*)alloc((size_t)CHE * 128 * 4);   // per-chunk; reused
  float*  os1   = Wab;    // alias: Wab dead before k_os1 runs
  float4* Yr_csr = (float4*)alloc((size_t)EE * 16);
  int* idxj_csr = (int*)alloc((size_t)EE * 4);
  float* Wv     = (float*)alloc((size_t)8192 * 4);
  int* cnt      = (int*)alloc((size_t)NN * 4);
  int* offs     = (int*)alloc((size_t)(NN + 1) * 4);
  int* pos      = (int*)alloc((size_t)EE * 4);
  int* elist    = (int*)alloc((size_t)EE * 4);

  hipMemsetAsync(cnt, 0, (size_t)NN * 4, stream);
  hipMemsetAsync(nagg, 0, (size_t)NN * 256 * 4, stream);
  k_count<<<EE / 256, 256, 0, stream>>>(idx_i, cnt, pos);
  k_scan<<<1, 256, 0, stream>>>(cnt, offs);
  k_fill<<<EE / 256, 256, 0, stream>>>(idx_i, idx_j, Yr, pos, offs,
                                       elist, idxj_csr, Yr_csr);
  k_embed<<<NN * 8 / 256, 256, 0, stream>>>(x, w_s, w_v, hsv);
  k_wv<<<32, 256, 0, stream>>>(w1v, w2v, Wv);
  for (int ch = 0; ch < NCH; ch++) {
    int c0 = ch * CHE, c1 = c0 + CHE;
    k_wab<<<CHE / 64, 256, 0, stream>>>(fij, rcut, elist, W1, b1, W2, b2,
                                        Wab, c0);
    k_agg<<<NN / 4, 256, 0, stream>>>((const float2*)Wab, Yr_csr, idxj_csr,
                                      hsv, offs, nagg, c0, c1);
  }
  k_os1<<<NN / 16, 256, 0, stream>>>(nagg, w1s, os1);
  k_os2<<<NN / 16, 256, 0, stream>>>(os1, w2s, out);
  k_ov<<<NN / 16, 256, 0, stream>>>(nagg, Wv, out);
}